// Round 10
// baseline (81.334 us; speedup 1.0000x reference)
//
#include <hip/hip_runtime.h>

constexpr int N_NODES = 50000;
constexpr int KNB = 12;       // neighbors per node
constexpr int F = 128;        // F_IN == F_OUT
constexpr float ALPHA = 0.2f; // LeakyReLU slope
constexpr int BM = 64;        // nodes per GEMM tile
constexpr int TILES_PER_BLK = 2;
constexpr int ATTN_NODES_PER_BLK = 32;                 // 4 waves x 4 groups x 2 nodes
constexpr int ATTN_NBLK = (N_NODES + ATTN_NODES_PER_BLK - 1) / ATTN_NODES_PER_BLK;  // 1563

typedef __bf16 bf16x8 __attribute__((ext_vector_type(8)));
typedef __bf16 bf16x2 __attribute__((ext_vector_type(2)));
typedef float  f32x4  __attribute__((ext_vector_type(4)));

// Native f32->bf16 pack: compiler emits v_cvt_pk_bf16_f32 (hardware RNE).
__device__ __forceinline__ unsigned pack2(float lo, float hi) {
    bf16x2 v;
    v[0] = (__bf16)lo;
    v[1] = (__bf16)hi;
    return __builtin_bit_cast(unsigned, v);
}
__device__ __forceinline__ float bf2f(unsigned bits16) {
    return __uint_as_float(bits16 << 16);
}

// ---------------- Kernel 0: W transpose + bf16, PRE-SWIZZLED ----------------
__global__ __launch_bounds__(256) void gat_prep(const float* __restrict__ Wself,
                                                const float* __restrict__ Wnb,
                                                unsigned* __restrict__ Wt) {
    const int gid = blockIdx.x * 256 + threadIdx.x;  // 16384 total
    const int n  = gid >> 6;
    const int kp = gid & 63;        // k-pair 0..63
    const int k16 = kp >> 2;
    const int sub = kp & 3;
    const float* src = (n < F) ? (Wself + n) : (Wnb + (n - F));
    const float f0 = src[(size_t)(kp * 2)     * F];
    const float f1 = src[(size_t)(kp * 2 + 1) * F];
    Wt[n * 64 + (k16 ^ (n & 7)) * 4 + sub] = pack2(f0, f1);
}

// ---------------- Kernel 1: fused dual GEMM via MFMA (unchanged from R9) ----------------
__global__ __launch_bounds__(512, 4) void gat_gemm(
    const float* __restrict__ x,
    const unsigned* __restrict__ Wt,   // [256][16] uint4, pre-swizzled
    const float* __restrict__ a,
    const float* __restrict__ bias,
    unsigned short* __restrict__ selfb,
    unsigned short* __restrict__ hb,
    float* __restrict__ s_in,
    float* __restrict__ s_out)
{
    __shared__ uint4 ldsX[BM * 16];    // 16KB
    __shared__ uint4 ldsW[256 * 16];   // 64KB

    const int t = threadIdx.x;
    const int w    = t >> 6;     // 0..7
    const int lane = t & 63;
    const int lq   = lane >> 4;
    const int lr   = lane & 15;

    const uint4* Wt4 = reinterpret_cast<const uint4*>(Wt);
#pragma unroll
    for (int i = 0; i < 8; ++i) {
        const int ch = w * 8 + i;
        const uint4* gp = Wt4 + ch * 64 + lane;
        uint4* lp = ldsW + ch * 64;
        __builtin_amdgcn_global_load_lds(
            (const __attribute__((address_space(1))) void*)gp,
            (__attribute__((address_space(3))) void*)lp, 16, 0, 0);
    }

    const bf16x8* fx = reinterpret_cast<const bf16x8*>(ldsX);
    const bf16x8* fw = reinterpret_cast<const bf16x8*>(ldsW);
    float* sbuf = reinterpret_cast<float*>(ldsX);

    for (int it = 0; it < TILES_PER_BLK; ++it) {
        const int base = (blockIdx.x * TILES_PER_BLK + it) * BM;

#pragma unroll
        for (int i = 0; i < 2; ++i) {
            const int idx = t + i * 512;       // row*16 + k16, 0..1023
            const int row = idx >> 4;
            const int k16 = idx & 15;
            int gr = base + row; if (gr >= N_NODES) gr = N_NODES - 1;
            const float4* xp = reinterpret_cast<const float4*>(x + (size_t)gr * F + k16 * 8);
            const float4 f0 = xp[0];
            const float4 f1 = xp[1];
            uint4 v;
            v.x = pack2(f0.x, f0.y); v.y = pack2(f0.z, f0.w);
            v.z = pack2(f1.x, f1.y); v.w = pack2(f1.z, f1.w);
            ldsX[row * 16 + (k16 ^ (row & 7))] = v;
        }
        __syncthreads();

        f32x4 acc[2][4];
#pragma unroll
        for (int mt = 0; mt < 2; ++mt)
#pragma unroll
            for (int rt = 0; rt < 4; ++rt)
                acc[mt][rt] = f32x4{0.f, 0.f, 0.f, 0.f};

#pragma unroll
        for (int s = 0; s < 4; ++s) {
            bf16x8 wf[2], xf[4];
#pragma unroll
            for (int mt = 0; mt < 2; ++mt) {
                const int n = w * 32 + mt * 16 + lr;
                wf[mt] = fw[n * 16 + ((s * 4 + lq) ^ (n & 7))];
            }
#pragma unroll
            for (int rt = 0; rt < 4; ++rt) {
                const int r = rt * 16 + lr;
                xf[rt] = fx[r * 16 + ((s * 4 + lq) ^ (r & 7))];
            }
#pragma unroll
            for (int mt = 0; mt < 2; ++mt)
#pragma unroll
                for (int rt = 0; rt < 4; ++rt)
                    acc[mt][rt] = __builtin_amdgcn_mfma_f32_16x16x32_bf16(wf[mt], xf[rt], acc[mt][rt], 0, 0, 0);
        }

        __syncthreads();

        if (w < 4) {
#pragma unroll
            for (int mt = 0; mt < 2; ++mt) {
                const int col0 = w * 32 + mt * 16 + lq * 4;
                const float4 b4 = *reinterpret_cast<const float4*>(bias + col0);
#pragma unroll
                for (int rt = 0; rt < 4; ++rt) {
                    const int row = base + rt * 16 + lr;
                    if (row < N_NODES) {
                        const f32x4 v = acc[mt][rt];
                        uint2 pk{pack2(v[0] + b4.x, v[1] + b4.y), pack2(v[2] + b4.z, v[3] + b4.w)};
                        *reinterpret_cast<uint2*>(selfb + (size_t)row * F + col0) = pk;
                    }
                }
            }
        } else {
            float spin[4] = {0.f, 0.f, 0.f, 0.f};
            float spout[4] = {0.f, 0.f, 0.f, 0.f};
#pragma unroll
            for (int mt = 0; mt < 2; ++mt) {
                const int colh0 = (w - 4) * 32 + mt * 16 + lq * 4;
                const float4 al = *reinterpret_cast<const float4*>(a + colh0);
                const float4 ah = *reinterpret_cast<const float4*>(a + F + colh0);
#pragma unroll
                for (int rt = 0; rt < 4; ++rt) {
                    const int row = base + rt * 16 + lr;
                    const f32x4 v = acc[mt][rt];
                    if (row < N_NODES) {
                        uint2 pk{pack2(v[0], v[1]), pack2(v[2], v[3])};
                        *reinterpret_cast<uint2*>(hb + (size_t)row * F + colh0) = pk;
                    }
                    spin[rt]  = fmaf(v[0], al.x, fmaf(v[1], al.y, fmaf(v[2], al.z, fmaf(v[3], al.w, spin[rt]))));
                    spout[rt] = fmaf(v[0], ah.x, fmaf(v[1], ah.y, fmaf(v[2], ah.z, fmaf(v[3], ah.w, spout[rt]))));
                }
            }
#pragma unroll
            for (int rt = 0; rt < 4; ++rt) {
                spin[rt]  += __shfl_xor(spin[rt], 16);
                spin[rt]  += __shfl_xor(spin[rt], 32);
                spout[rt] += __shfl_xor(spout[rt], 16);
                spout[rt] += __shfl_xor(spout[rt], 32);
            }
            if (lq == 0) {
#pragma unroll
                for (int rt = 0; rt < 4; ++rt) {
                    sbuf[(w - 4) * 128 + rt * 16 + lr]      = spin[rt];
                    sbuf[(w - 4) * 128 + 64 + rt * 16 + lr] = spout[rt];
                }
            }
        }
        __syncthreads();
        if (t < 128) {
            const int i = t & 63;
            const int row = base + i;
            if (row < N_NODES) {
                if (t < 64) s_in[row]  = sbuf[i]      + sbuf[128 + i] + sbuf[256 + i] + sbuf[384 + i];
                else        s_out[row] = sbuf[64 + i] + sbuf[192 + i] + sbuf[320 + i] + sbuf[448 + i];
            }
        }
        __syncthreads();
    }
}

// ---------------- Kernel 2: attention + aggregation, 2 nodes per 16-lane group ----------------
// 8 nodes/wave, 24 independent uint4 gathers in flight per wave (2x MLP vs R9).
// MEASUREMENT: grid is 2*ATTN_NBLK; blocks >= ATTN_NBLK redo the same nodes
// (idempotent) so the dispatch exceeds the ~41us fill dispatches and surfaces
// in rocprof top-5 with counters.
__global__ __launch_bounds__(256) void gat_attn(
    const uint4* __restrict__ hbU4,      // h bf16: [N][16] uint4
    const uint4* __restrict__ selfbU4,   // act_self+bias bf16: [N][16] uint4
    const float* __restrict__ s_in,
    const float* __restrict__ s_out,
    const int* __restrict__ colidx,
    const float* __restrict__ adj,
    float* __restrict__ out)
{
    int blk = blockIdx.x;
    if (blk >= ATTN_NBLK) blk -= ATTN_NBLK;   // doubled-grid measurement fold

    const int t = threadIdx.x;
    const int wid  = t >> 6;
    const int lane = t & 63;
    const int lr   = lane & 15;
    const int grp  = lane >> 4;               // 0..3
    const int nodeA = blk * ATTN_NODES_PER_BLK + wid * 8 + grp * 2;
    const int nodeB = nodeA + 1;
    const bool vA = nodeA < N_NODES;
    const bool vB = nodeB < N_NODES;

    // ---- scores for both nodes (lanes lr<12 hold edges) ----
    float eA = -1e30f, eB = -1e30f;
    int   cA = 0, cB = 0;
    float avA = 0.f, avB = 0.f;
    if (lr < KNB) {
        if (vA) {
            cA  = colidx[nodeA * KNB + lr];
            avA = adj[nodeA * KNB + lr];
            const float ev = s_in[nodeA] + s_out[cA];
            eA = ev > 0.f ? ev : ALPHA * ev;
        }
        if (vB) {
            cB  = colidx[nodeB * KNB + lr];
            avB = adj[nodeB * KNB + lr];
            const float ev = s_in[nodeB] + s_out[cB];
            eB = ev > 0.f ? ev : ALPHA * ev;
        }
    }
    float mA = eA, mB = eB;
#pragma unroll
    for (int msk = 8; msk >= 1; msk >>= 1) {
        mA = fmaxf(mA, __shfl_xor(mA, msk));
        mB = fmaxf(mB, __shfl_xor(mB, msk));
    }
    const float pA = (lr < KNB) ? __expf(eA - mA) : 0.f;
    const float pB = (lr < KNB) ? __expf(eB - mB) : 0.f;
    float sA = pA, sB = pB;
#pragma unroll
    for (int msk = 8; msk >= 1; msk >>= 1) {
        sA += __shfl_xor(sA, msk);
        sB += __shfl_xor(sB, msk);
    }
    const float attA = pA / sA * avA;
    const float attB = pB / sB * avB;

    // ---- base: self contribution ----
    float fA[8], fB[8];
    {
        const uint4 sbA = selfbU4[(size_t)(vA ? nodeA : 0) * 16 + lr];
        const uint4 sbB = selfbU4[(size_t)(vB ? nodeB : 0) * 16 + lr];
        fA[0] = bf2f(sbA.x & 0xffffu); fA[1] = bf2f(sbA.x >> 16);
        fA[2] = bf2f(sbA.y & 0xffffu); fA[3] = bf2f(sbA.y >> 16);
        fA[4] = bf2f(sbA.z & 0xffffu); fA[5] = bf2f(sbA.z >> 16);
        fA[6] = bf2f(sbA.w & 0xffffu); fA[7] = bf2f(sbA.w >> 16);
        fB[0] = bf2f(sbB.x & 0xffffu); fB[1] = bf2f(sbB.x >> 16);
        fB[2] = bf2f(sbB.y & 0xffffu); fB[3] = bf2f(sbB.y >> 16);
        fB[4] = bf2f(sbB.z & 0xffffu); fB[5] = bf2f(sbB.z >> 16);
        fB[6] = bf2f(sbB.w & 0xffffu); fB[7] = bf2f(sbB.w >> 16);
    }

    // ---- gather loop: 24 independent uint4 loads in flight per wave ----
    const int gb = lane & 48;
#pragma unroll
    for (int j = 0; j < KNB; ++j) {
        const float ajA = __shfl(attA, gb + j);
        const int   cjA = __shfl(cA,   gb + j);
        const float ajB = __shfl(attB, gb + j);
        const int   cjB = __shfl(cB,   gb + j);
        const uint4 uA = hbU4[(size_t)cjA * 16 + lr];
        const uint4 uB = hbU4[(size_t)cjB * 16 + lr];
        fA[0] = fmaf(ajA, bf2f(uA.x & 0xffffu), fA[0]);
        fA[1] = fmaf(ajA, bf2f(uA.x >> 16),     fA[1]);
        fA[2] = fmaf(ajA, bf2f(uA.y & 0xffffu), fA[2]);
        fA[3] = fmaf(ajA, bf2f(uA.y >> 16),     fA[3]);
        fA[4] = fmaf(ajA, bf2f(uA.z & 0xffffu), fA[4]);
        fA[5] = fmaf(ajA, bf2f(uA.z >> 16),     fA[5]);
        fA[6] = fmaf(ajA, bf2f(uA.w & 0xffffu), fA[6]);
        fA[7] = fmaf(ajA, bf2f(uA.w >> 16),     fA[7]);
        fB[0] = fmaf(ajB, bf2f(uB.x & 0xffffu), fB[0]);
        fB[1] = fmaf(ajB, bf2f(uB.x >> 16),     fB[1]);
        fB[2] = fmaf(ajB, bf2f(uB.y & 0xffffu), fB[2]);
        fB[3] = fmaf(ajB, bf2f(uB.y >> 16),     fB[3]);
        fB[4] = fmaf(ajB, bf2f(uB.z & 0xffffu), fB[4]);
        fB[5] = fmaf(ajB, bf2f(uB.z >> 16),     fB[5]);
        fB[6] = fmaf(ajB, bf2f(uB.w & 0xffffu), fB[6]);
        fB[7] = fmaf(ajB, bf2f(uB.w >> 16),     fB[7]);
    }

    if (vA) {
        float4* op = reinterpret_cast<float4*>(out + (size_t)nodeA * F + lr * 8);
        op[0] = float4{fA[0], fA[1], fA[2], fA[3]};
        op[1] = float4{fA[4], fA[5], fA[6], fA[7]};
    }
    if (vB) {
        float4* op = reinterpret_cast<float4*>(out + (size_t)nodeB * F + lr * 8);
        op[0] = float4{fB[0], fB[1], fB[2], fB[3]};
        op[1] = float4{fB[4], fB[5], fB[6], fB[7]};
    }
}

extern "C" void kernel_launch(void* const* d_in, const int* in_sizes, int n_in,
                              void* d_out, int out_size, void* d_ws, size_t ws_size,
                              hipStream_t stream) {
    const float* x     = (const float*)d_in[0];
    const float* adj   = (const float*)d_in[1];
    // d_in[2] = row: implicit (edges sorted, exactly K per node)
    const int*   col   = (const int*)d_in[3];
    const float* Wself = (const float*)d_in[4];
    const float* Wnb   = (const float*)d_in[5];
    const float* a     = (const float*)d_in[6];
    const float* bias  = (const float*)d_in[7];
    float* out = (float*)d_out;

    char* ws = (char*)d_ws;
    unsigned short* hb    = (unsigned short*)ws;         // 12,800,000 B
    unsigned short* selfb = (unsigned short*)(ws + 12800000);  // 12,800,000 B
    float* s_in  = (float*)(ws + 25600000);              // 200,000 B
    float* s_out = (float*)(ws + 25800000);              // 200,000 B
    unsigned* Wt = (unsigned*)(ws + 26000000);           // 65,536 B

    gat_prep<<<64, 256, 0, stream>>>(Wself, Wnb, Wt);
    const int ntiles = (N_NODES + BM - 1) / BM;                       // 782
    const int nblk   = (ntiles + TILES_PER_BLK - 1) / TILES_PER_BLK;  // 391
    gat_gemm<<<nblk, 512, 0, stream>>>(x, Wt, a, bias, selfb, hb, s_in, s_out);
    // MEASUREMENT: doubled grid (idempotent duplicate pass) to surface attn
    // counters above the ~41us fill dispatches in rocprof's top-5.
    gat_attn<<<2 * ATTN_NBLK, 256, 0, stream>>>((const uint4*)hb, (const uint4*)selfb,
                                                s_in, s_out, col, adj, out);
}

// Round 11
// 58.404 us; speedup vs baseline: 1.3926x; 1.3926x over previous
//
#include <hip/hip_runtime.h>

constexpr int N_NODES = 50000;
constexpr int KNB = 12;       // neighbors per node
constexpr int F = 128;        // F_IN == F_OUT
constexpr float ALPHA = 0.2f; // LeakyReLU slope
constexpr int BM = 64;        // nodes per GEMM tile
constexpr int TILES_PER_BLK = 2;
constexpr int ATTN_NODES_PER_BLK = 32;                 // 4 waves x 4 groups x 2 nodes
constexpr int ATTN_NBLK = (N_NODES + ATTN_NODES_PER_BLK - 1) / ATTN_NODES_PER_BLK;  // 1563

typedef __bf16 bf16x8 __attribute__((ext_vector_type(8)));
typedef __bf16 bf16x2 __attribute__((ext_vector_type(2)));
typedef float  f32x4  __attribute__((ext_vector_type(4)));
typedef unsigned u32x4 __attribute__((ext_vector_type(4)));

// Native f32->bf16 pack: compiler emits v_cvt_pk_bf16_f32 (hardware RNE).
__device__ __forceinline__ unsigned pack2(float lo, float hi) {
    bf16x2 v;
    v[0] = (__bf16)lo;
    v[1] = (__bf16)hi;
    return __builtin_bit_cast(unsigned, v);
}
__device__ __forceinline__ float bf2f(unsigned bits16) {
    return __uint_as_float(bits16 << 16);
}

// ---------------- Kernel 0: W transpose + bf16, PRE-SWIZZLED ----------------
__global__ __launch_bounds__(256) void gat_prep(const float* __restrict__ Wself,
                                                const float* __restrict__ Wnb,
                                                unsigned* __restrict__ Wt) {
    const int gid = blockIdx.x * 256 + threadIdx.x;  // 16384 total
    const int n  = gid >> 6;
    const int kp = gid & 63;        // k-pair 0..63
    const int k16 = kp >> 2;
    const int sub = kp & 3;
    const float* src = (n < F) ? (Wself + n) : (Wnb + (n - F));
    const float f0 = src[(size_t)(kp * 2)     * F];
    const float f1 = src[(size_t)(kp * 2 + 1) * F];
    Wt[n * 64 + (k16 ^ (n & 7)) * 4 + sub] = pack2(f0, f1);
}

// ---------------- Kernel 1: fused dual GEMM via MFMA ----------------
// x loads are NON-TEMPORAL (read exactly once) to avoid evicting hb/selfb.
__global__ __launch_bounds__(512, 4) void gat_gemm(
    const float* __restrict__ x,
    const unsigned* __restrict__ Wt,   // [256][16] uint4, pre-swizzled
    const float* __restrict__ a,
    const float* __restrict__ bias,
    unsigned short* __restrict__ selfb,
    unsigned short* __restrict__ hb,
    float* __restrict__ s_in,
    float* __restrict__ s_out)
{
    __shared__ uint4 ldsX[BM * 16];    // 16KB
    __shared__ uint4 ldsW[256 * 16];   // 64KB

    const int t = threadIdx.x;
    const int w    = t >> 6;     // 0..7
    const int lane = t & 63;
    const int lq   = lane >> 4;
    const int lr   = lane & 15;

    const uint4* Wt4 = reinterpret_cast<const uint4*>(Wt);
#pragma unroll
    for (int i = 0; i < 8; ++i) {
        const int ch = w * 8 + i;
        const uint4* gp = Wt4 + ch * 64 + lane;
        uint4* lp = ldsW + ch * 64;
        __builtin_amdgcn_global_load_lds(
            (const __attribute__((address_space(1))) void*)gp,
            (__attribute__((address_space(3))) void*)lp, 16, 0, 0);
    }

    const bf16x8* fx = reinterpret_cast<const bf16x8*>(ldsX);
    const bf16x8* fw = reinterpret_cast<const bf16x8*>(ldsW);
    float* sbuf = reinterpret_cast<float*>(ldsX);

    for (int it = 0; it < TILES_PER_BLK; ++it) {
        const int base = (blockIdx.x * TILES_PER_BLK + it) * BM;

#pragma unroll
        for (int i = 0; i < 2; ++i) {
            const int idx = t + i * 512;       // row*16 + k16, 0..1023
            const int row = idx >> 4;
            const int k16 = idx & 15;
            int gr = base + row; if (gr >= N_NODES) gr = N_NODES - 1;
            const f32x4* xp = reinterpret_cast<const f32x4*>(x + (size_t)gr * F + k16 * 8);
            const f32x4 f0 = __builtin_nontemporal_load(xp);
            const f32x4 f1 = __builtin_nontemporal_load(xp + 1);
            uint4 v;
            v.x = pack2(f0[0], f0[1]); v.y = pack2(f0[2], f0[3]);
            v.z = pack2(f1[0], f1[1]); v.w = pack2(f1[2], f1[3]);
            ldsX[row * 16 + (k16 ^ (row & 7))] = v;
        }
        __syncthreads();

        f32x4 acc[2][4];
#pragma unroll
        for (int mt = 0; mt < 2; ++mt)
#pragma unroll
            for (int rt = 0; rt < 4; ++rt)
                acc[mt][rt] = f32x4{0.f, 0.f, 0.f, 0.f};

#pragma unroll
        for (int s = 0; s < 4; ++s) {
            bf16x8 wf[2], xf[4];
#pragma unroll
            for (int mt = 0; mt < 2; ++mt) {
                const int n = w * 32 + mt * 16 + lr;
                wf[mt] = fw[n * 16 + ((s * 4 + lq) ^ (n & 7))];
            }
#pragma unroll
            for (int rt = 0; rt < 4; ++rt) {
                const int r = rt * 16 + lr;
                xf[rt] = fx[r * 16 + ((s * 4 + lq) ^ (r & 7))];
            }
#pragma unroll
            for (int mt = 0; mt < 2; ++mt)
#pragma unroll
                for (int rt = 0; rt < 4; ++rt)
                    acc[mt][rt] = __builtin_amdgcn_mfma_f32_16x16x32_bf16(wf[mt], xf[rt], acc[mt][rt], 0, 0, 0);
        }

        __syncthreads();

        if (w < 4) {
#pragma unroll
            for (int mt = 0; mt < 2; ++mt) {
                const int col0 = w * 32 + mt * 16 + lq * 4;
                const float4 b4 = *reinterpret_cast<const float4*>(bias + col0);
#pragma unroll
                for (int rt = 0; rt < 4; ++rt) {
                    const int row = base + rt * 16 + lr;
                    if (row < N_NODES) {
                        const f32x4 v = acc[mt][rt];
                        uint2 pk{pack2(v[0] + b4.x, v[1] + b4.y), pack2(v[2] + b4.z, v[3] + b4.w)};
                        *reinterpret_cast<uint2*>(selfb + (size_t)row * F + col0) = pk;
                    }
                }
            }
        } else {
            float spin[4] = {0.f, 0.f, 0.f, 0.f};
            float spout[4] = {0.f, 0.f, 0.f, 0.f};
#pragma unroll
            for (int mt = 0; mt < 2; ++mt) {
                const int colh0 = (w - 4) * 32 + mt * 16 + lq * 4;
                const float4 al = *reinterpret_cast<const float4*>(a + colh0);
                const float4 ah = *reinterpret_cast<const float4*>(a + F + colh0);
#pragma unroll
                for (int rt = 0; rt < 4; ++rt) {
                    const int row = base + rt * 16 + lr;
                    const f32x4 v = acc[mt][rt];
                    if (row < N_NODES) {
                        uint2 pk{pack2(v[0], v[1]), pack2(v[2], v[3])};
                        *reinterpret_cast<uint2*>(hb + (size_t)row * F + colh0) = pk;
                    }
                    spin[rt]  = fmaf(v[0], al.x, fmaf(v[1], al.y, fmaf(v[2], al.z, fmaf(v[3], al.w, spin[rt]))));
                    spout[rt] = fmaf(v[0], ah.x, fmaf(v[1], ah.y, fmaf(v[2], ah.z, fmaf(v[3], ah.w, spout[rt]))));
                }
            }
#pragma unroll
            for (int rt = 0; rt < 4; ++rt) {
                spin[rt]  += __shfl_xor(spin[rt], 16);
                spin[rt]  += __shfl_xor(spin[rt], 32);
                spout[rt] += __shfl_xor(spout[rt], 16);
                spout[rt] += __shfl_xor(spout[rt], 32);
            }
            if (lq == 0) {
#pragma unroll
                for (int rt = 0; rt < 4; ++rt) {
                    sbuf[(w - 4) * 128 + rt * 16 + lr]      = spin[rt];
                    sbuf[(w - 4) * 128 + 64 + rt * 16 + lr] = spout[rt];
                }
            }
        }
        __syncthreads();
        if (t < 128) {
            const int i = t & 63;
            const int row = base + i;
            if (row < N_NODES) {
                if (t < 64) s_in[row]  = sbuf[i]      + sbuf[128 + i] + sbuf[256 + i] + sbuf[384 + i];
                else        s_out[row] = sbuf[64 + i] + sbuf[192 + i] + sbuf[320 + i] + sbuf[448 + i];
            }
        }
        __syncthreads();
    }
}

// ---------------- Kernel 2: attention + aggregation ----------------
// 2 nodes per 16-lane group. selfb via NON-TEMPORAL loads (read once);
// out via NON-TEMPORAL stores (never re-read: no write-allocate, no pollution).
__global__ __launch_bounds__(256) void gat_attn(
    const u32x4* __restrict__ hbU4,      // h bf16: [N][16] x u32x4
    const u32x4* __restrict__ selfbU4,   // act_self+bias bf16
    const float* __restrict__ s_in,
    const float* __restrict__ s_out,
    const int* __restrict__ colidx,
    const float* __restrict__ adj,
    float* __restrict__ out)
{
    const int blk = blockIdx.x;
    const int t = threadIdx.x;
    const int wid  = t >> 6;
    const int lane = t & 63;
    const int lr   = lane & 15;
    const int grp  = lane >> 4;               // 0..3
    const int nodeA = blk * ATTN_NODES_PER_BLK + wid * 8 + grp * 2;
    const int nodeB = nodeA + 1;
    const bool vA = nodeA < N_NODES;
    const bool vB = nodeB < N_NODES;

    float eA = -1e30f, eB = -1e30f;
    int   cA = 0, cB = 0;
    float avA = 0.f, avB = 0.f;
    if (lr < KNB) {
        if (vA) {
            cA  = colidx[nodeA * KNB + lr];
            avA = adj[nodeA * KNB + lr];
            const float ev = s_in[nodeA] + s_out[cA];
            eA = ev > 0.f ? ev : ALPHA * ev;
        }
        if (vB) {
            cB  = colidx[nodeB * KNB + lr];
            avB = adj[nodeB * KNB + lr];
            const float ev = s_in[nodeB] + s_out[cB];
            eB = ev > 0.f ? ev : ALPHA * ev;
        }
    }
    float mA = eA, mB = eB;
#pragma unroll
    for (int msk = 8; msk >= 1; msk >>= 1) {
        mA = fmaxf(mA, __shfl_xor(mA, msk));
        mB = fmaxf(mB, __shfl_xor(mB, msk));
    }
    const float pA = (lr < KNB) ? __expf(eA - mA) : 0.f;
    const float pB = (lr < KNB) ? __expf(eB - mB) : 0.f;
    float sA = pA, sB = pB;
#pragma unroll
    for (int msk = 8; msk >= 1; msk >>= 1) {
        sA += __shfl_xor(sA, msk);
        sB += __shfl_xor(sB, msk);
    }
    const float attA = pA / sA * avA;
    const float attB = pB / sB * avB;

    float fA[8], fB[8];
    {
        const u32x4 sbA = __builtin_nontemporal_load(selfbU4 + (size_t)(vA ? nodeA : 0) * 16 + lr);
        const u32x4 sbB = __builtin_nontemporal_load(selfbU4 + (size_t)(vB ? nodeB : 0) * 16 + lr);
        fA[0] = bf2f(sbA[0] & 0xffffu); fA[1] = bf2f(sbA[0] >> 16);
        fA[2] = bf2f(sbA[1] & 0xffffu); fA[3] = bf2f(sbA[1] >> 16);
        fA[4] = bf2f(sbA[2] & 0xffffu); fA[5] = bf2f(sbA[2] >> 16);
        fA[6] = bf2f(sbA[3] & 0xffffu); fA[7] = bf2f(sbA[3] >> 16);
        fB[0] = bf2f(sbB[0] & 0xffffu); fB[1] = bf2f(sbB[0] >> 16);
        fB[2] = bf2f(sbB[1] & 0xffffu); fB[3] = bf2f(sbB[1] >> 16);
        fB[4] = bf2f(sbB[2] & 0xffffu); fB[5] = bf2f(sbB[2] >> 16);
        fB[6] = bf2f(sbB[3] & 0xffffu); fB[7] = bf2f(sbB[3] >> 16);
    }

    const int gb = lane & 48;
#pragma unroll
    for (int j = 0; j < KNB; ++j) {
        const float ajA = __shfl(attA, gb + j);
        const int   cjA = __shfl(cA,   gb + j);
        const float ajB = __shfl(attB, gb + j);
        const int   cjB = __shfl(cB,   gb + j);
        const u32x4 uA = hbU4[(size_t)cjA * 16 + lr];
        const u32x4 uB = hbU4[(size_t)cjB * 16 + lr];
        fA[0] = fmaf(ajA, bf2f(uA[0] & 0xffffu), fA[0]);
        fA[1] = fmaf(ajA, bf2f(uA[0] >> 16),     fA[1]);
        fA[2] = fmaf(ajA, bf2f(uA[1] & 0xffffu), fA[2]);
        fA[3] = fmaf(ajA, bf2f(uA[1] >> 16),     fA[3]);
        fA[4] = fmaf(ajA, bf2f(uA[2] & 0xffffu), fA[4]);
        fA[5] = fmaf(ajA, bf2f(uA[2] >> 16),     fA[5]);
        fA[6] = fmaf(ajA, bf2f(uA[3] & 0xffffu), fA[6]);
        fA[7] = fmaf(ajA, bf2f(uA[3] >> 16),     fA[7]);
        fB[0] = fmaf(ajB, bf2f(uB[0] & 0xffffu), fB[0]);
        fB[1] = fmaf(ajB, bf2f(uB[0] >> 16),     fB[1]);
        fB[2] = fmaf(ajB, bf2f(uB[1] & 0xffffu), fB[2]);
        fB[3] = fmaf(ajB, bf2f(uB[1] >> 16),     fB[3]);
        fB[4] = fmaf(ajB, bf2f(uB[2] & 0xffffu), fB[4]);
        fB[5] = fmaf(ajB, bf2f(uB[2] >> 16),     fB[5]);
        fB[6] = fmaf(ajB, bf2f(uB[3] & 0xffffu), fB[6]);
        fB[7] = fmaf(ajB, bf2f(uB[3] >> 16),     fB[7]);
    }

    if (vA) {
        f32x4* op = reinterpret_cast<f32x4*>(out + (size_t)nodeA * F + lr * 8);
        __builtin_nontemporal_store(f32x4{fA[0], fA[1], fA[2], fA[3]}, op);
        __builtin_nontemporal_store(f32x4{fA[4], fA[5], fA[6], fA[7]}, op + 1);
    }
    if (vB) {
        f32x4* op = reinterpret_cast<f32x4*>(out + (size_t)nodeB * F + lr * 8);
        __builtin_nontemporal_store(f32x4{fB[0], fB[1], fB[2], fB[3]}, op);
        __builtin_nontemporal_store(f32x4{fB[4], fB[5], fB[6], fB[7]}, op + 1);
    }
}

extern "C" void kernel_launch(void* const* d_in, const int* in_sizes, int n_in,
                              void* d_out, int out_size, void* d_ws, size_t ws_size,
                              hipStream_t stream) {
    const float* x     = (const float*)d_in[0];
    const float* adj   = (const float*)d_in[1];
    // d_in[2] = row: implicit (edges sorted, exactly K per node)
    const int*   col   = (const int*)d_in[3];
    const float* Wself = (const float*)d_in[4];
    const float* Wnb   = (const float*)d_in[5];
    const float* a     = (const float*)d_in[6];
    const float* bias  = (const float*)d_in[7];
    float* out = (float*)d_out;

    char* ws = (char*)d_ws;
    unsigned short* hb    = (unsigned short*)ws;         // 12,800,000 B
    unsigned short* selfb = (unsigned short*)(ws + 12800000);  // 12,800,000 B
    float* s_in  = (float*)(ws + 25600000);              // 200,000 B
    float* s_out = (float*)(ws + 25800000);              // 200,000 B
    unsigned* Wt = (unsigned*)(ws + 26000000);           // 65,536 B

    gat_prep<<<64, 256, 0, stream>>>(Wself, Wnb, Wt);
    const int ntiles = (N_NODES + BM - 1) / BM;                       // 782
    const int nblk   = (ntiles + TILES_PER_BLK - 1) / TILES_PER_BLK;  // 391
    gat_gemm<<<nblk, 512, 0, stream>>>(x, Wt, a, bias, selfb, hb, s_in, s_out);
    gat_attn<<<ATTN_NBLK, 256, 0, stream>>>((const u32x4*)hb, (const u32x4*)selfb,
                                            s_in, s_out, col, adj, out);
}

// Round 12
// 54.973 us; speedup vs baseline: 1.4795x; 1.0624x over previous
//
#include <hip/hip_runtime.h>

constexpr int N_NODES = 50000;
constexpr int KNB = 12;       // neighbors per node
constexpr int F = 128;        // F_IN == F_OUT
constexpr float ALPHA = 0.2f; // LeakyReLU slope
constexpr int BM = 64;        // nodes per GEMM tile
constexpr int TILES_PER_BLK = 2;
constexpr int ATTN_NODES_PER_BLK = 32;                 // 4 waves x 4 groups x 2 nodes
constexpr int ATTN_NBLK = (N_NODES + ATTN_NODES_PER_BLK - 1) / ATTN_NODES_PER_BLK;  // 1563

typedef __bf16 bf16x8 __attribute__((ext_vector_type(8)));
typedef __bf16 bf16x2 __attribute__((ext_vector_type(2)));
typedef float  f32x4  __attribute__((ext_vector_type(4)));
typedef unsigned u32x4 __attribute__((ext_vector_type(4)));

// Native f32->bf16 pack: compiler emits v_cvt_pk_bf16_f32 (hardware RNE).
__device__ __forceinline__ unsigned pack2(float lo, float hi) {
    bf16x2 v;
    v[0] = (__bf16)lo;
    v[1] = (__bf16)hi;
    return __builtin_bit_cast(unsigned, v);
}
__device__ __forceinline__ float bf2f(unsigned bits16) {
    return __uint_as_float(bits16 << 16);
}

// ---------------- Kernel 0: W transpose + bf16, PRE-SWIZZLED ----------------
__global__ __launch_bounds__(256) void gat_prep(const float* __restrict__ Wself,
                                                const float* __restrict__ Wnb,
                                                unsigned* __restrict__ Wt) {
    const int gid = blockIdx.x * 256 + threadIdx.x;  // 16384 total
    const int n  = gid >> 6;
    const int kp = gid & 63;        // k-pair 0..63
    const int k16 = kp >> 2;
    const int sub = kp & 3;
    const float* src = (n < F) ? (Wself + n) : (Wnb + (n - F));
    const float f0 = src[(size_t)(kp * 2)     * F];
    const float f1 = src[(size_t)(kp * 2 + 1) * F];
    Wt[n * 64 + (k16 ^ (n & 7)) * 4 + sub] = pack2(f0, f1);
}

// ---------------- Kernel 1: fused dual GEMM via MFMA (cached loads, as R9) ----------------
__global__ __launch_bounds__(512, 4) void gat_gemm(
    const float* __restrict__ x,
    const unsigned* __restrict__ Wt,   // [256][16] uint4, pre-swizzled
    const float* __restrict__ a,
    const float* __restrict__ bias,
    unsigned short* __restrict__ selfb,
    unsigned short* __restrict__ hb,
    float* __restrict__ s_in,
    float* __restrict__ s_out)
{
    __shared__ uint4 ldsX[BM * 16];    // 16KB
    __shared__ uint4 ldsW[256 * 16];   // 64KB

    const int t = threadIdx.x;
    const int w    = t >> 6;     // 0..7
    const int lane = t & 63;
    const int lq   = lane >> 4;
    const int lr   = lane & 15;

    const uint4* Wt4 = reinterpret_cast<const uint4*>(Wt);
#pragma unroll
    for (int i = 0; i < 8; ++i) {
        const int ch = w * 8 + i;
        const uint4* gp = Wt4 + ch * 64 + lane;
        uint4* lp = ldsW + ch * 64;
        __builtin_amdgcn_global_load_lds(
            (const __attribute__((address_space(1))) void*)gp,
            (__attribute__((address_space(3))) void*)lp, 16, 0, 0);
    }

    const bf16x8* fx = reinterpret_cast<const bf16x8*>(ldsX);
    const bf16x8* fw = reinterpret_cast<const bf16x8*>(ldsW);
    float* sbuf = reinterpret_cast<float*>(ldsX);

    for (int it = 0; it < TILES_PER_BLK; ++it) {
        const int base = (blockIdx.x * TILES_PER_BLK + it) * BM;

#pragma unroll
        for (int i = 0; i < 2; ++i) {
            const int idx = t + i * 512;       // row*16 + k16, 0..1023
            const int row = idx >> 4;
            const int k16 = idx & 15;
            int gr = base + row; if (gr >= N_NODES) gr = N_NODES - 1;
            const float4* xp = reinterpret_cast<const float4*>(x + (size_t)gr * F + k16 * 8);
            const float4 f0 = xp[0];
            const float4 f1 = xp[1];
            uint4 v;
            v.x = pack2(f0.x, f0.y); v.y = pack2(f0.z, f0.w);
            v.z = pack2(f1.x, f1.y); v.w = pack2(f1.z, f1.w);
            ldsX[row * 16 + (k16 ^ (row & 7))] = v;
        }
        __syncthreads();

        f32x4 acc[2][4];
#pragma unroll
        for (int mt = 0; mt < 2; ++mt)
#pragma unroll
            for (int rt = 0; rt < 4; ++rt)
                acc[mt][rt] = f32x4{0.f, 0.f, 0.f, 0.f};

#pragma unroll
        for (int s = 0; s < 4; ++s) {
            bf16x8 wf[2], xf[4];
#pragma unroll
            for (int mt = 0; mt < 2; ++mt) {
                const int n = w * 32 + mt * 16 + lr;
                wf[mt] = fw[n * 16 + ((s * 4 + lq) ^ (n & 7))];
            }
#pragma unroll
            for (int rt = 0; rt < 4; ++rt) {
                const int r = rt * 16 + lr;
                xf[rt] = fx[r * 16 + ((s * 4 + lq) ^ (r & 7))];
            }
#pragma unroll
            for (int mt = 0; mt < 2; ++mt)
#pragma unroll
                for (int rt = 0; rt < 4; ++rt)
                    acc[mt][rt] = __builtin_amdgcn_mfma_f32_16x16x32_bf16(wf[mt], xf[rt], acc[mt][rt], 0, 0, 0);
        }

        __syncthreads();

        if (w < 4) {
#pragma unroll
            for (int mt = 0; mt < 2; ++mt) {
                const int col0 = w * 32 + mt * 16 + lq * 4;
                const float4 b4 = *reinterpret_cast<const float4*>(bias + col0);
#pragma unroll
                for (int rt = 0; rt < 4; ++rt) {
                    const int row = base + rt * 16 + lr;
                    if (row < N_NODES) {
                        const f32x4 v = acc[mt][rt];
                        uint2 pk{pack2(v[0] + b4.x, v[1] + b4.y), pack2(v[2] + b4.z, v[3] + b4.w)};
                        *reinterpret_cast<uint2*>(selfb + (size_t)row * F + col0) = pk;
                    }
                }
            }
        } else {
            float spin[4] = {0.f, 0.f, 0.f, 0.f};
            float spout[4] = {0.f, 0.f, 0.f, 0.f};
#pragma unroll
            for (int mt = 0; mt < 2; ++mt) {
                const int colh0 = (w - 4) * 32 + mt * 16 + lq * 4;
                const float4 al = *reinterpret_cast<const float4*>(a + colh0);
                const float4 ah = *reinterpret_cast<const float4*>(a + F + colh0);
#pragma unroll
                for (int rt = 0; rt < 4; ++rt) {
                    const int row = base + rt * 16 + lr;
                    const f32x4 v = acc[mt][rt];
                    if (row < N_NODES) {
                        uint2 pk{pack2(v[0], v[1]), pack2(v[2], v[3])};
                        *reinterpret_cast<uint2*>(hb + (size_t)row * F + colh0) = pk;
                    }
                    spin[rt]  = fmaf(v[0], al.x, fmaf(v[1], al.y, fmaf(v[2], al.z, fmaf(v[3], al.w, spin[rt]))));
                    spout[rt] = fmaf(v[0], ah.x, fmaf(v[1], ah.y, fmaf(v[2], ah.z, fmaf(v[3], ah.w, spout[rt]))));
                }
            }
#pragma unroll
            for (int rt = 0; rt < 4; ++rt) {
                spin[rt]  += __shfl_xor(spin[rt], 16);
                spin[rt]  += __shfl_xor(spin[rt], 32);
                spout[rt] += __shfl_xor(spout[rt], 16);
                spout[rt] += __shfl_xor(spout[rt], 32);
            }
            if (lq == 0) {
#pragma unroll
                for (int rt = 0; rt < 4; ++rt) {
                    sbuf[(w - 4) * 128 + rt * 16 + lr]      = spin[rt];
                    sbuf[(w - 4) * 128 + 64 + rt * 16 + lr] = spout[rt];
                }
            }
        }
        __syncthreads();
        if (t < 128) {
            const int i = t & 63;
            const int row = base + i;
            if (row < N_NODES) {
                if (t < 64) s_in[row]  = sbuf[i]      + sbuf[128 + i] + sbuf[256 + i] + sbuf[384 + i];
                else        s_out[row] = sbuf[64 + i] + sbuf[192 + i] + sbuf[320 + i] + sbuf[448 + i];
            }
        }
        __syncthreads();
    }
}

// ---------------- Kernel 2: attention + aggregation ----------------
// 2 nodes per 16-lane group; cached loads for hb/selfb (L2/L3-resident);
// SINGLE nt change vs the 50.6us baseline: NON-TEMPORAL store on out only.
__global__ __launch_bounds__(256) void gat_attn(
    const u32x4* __restrict__ hbU4,      // h bf16: [N][16] x u32x4
    const u32x4* __restrict__ selfbU4,   // act_self+bias bf16
    const float* __restrict__ s_in,
    const float* __restrict__ s_out,
    const int* __restrict__ colidx,
    const float* __restrict__ adj,
    float* __restrict__ out)
{
    const int blk = blockIdx.x;
    const int t = threadIdx.x;
    const int wid  = t >> 6;
    const int lane = t & 63;
    const int lr   = lane & 15;
    const int grp  = lane >> 4;               // 0..3
    const int nodeA = blk * ATTN_NODES_PER_BLK + wid * 8 + grp * 2;
    const int nodeB = nodeA + 1;
    const bool vA = nodeA < N_NODES;
    const bool vB = nodeB < N_NODES;

    float eA = -1e30f, eB = -1e30f;
    int   cA = 0, cB = 0;
    float avA = 0.f, avB = 0.f;
    if (lr < KNB) {
        if (vA) {
            cA  = colidx[nodeA * KNB + lr];
            avA = adj[nodeA * KNB + lr];
            const float ev = s_in[nodeA] + s_out[cA];
            eA = ev > 0.f ? ev : ALPHA * ev;
        }
        if (vB) {
            cB  = colidx[nodeB * KNB + lr];
            avB = adj[nodeB * KNB + lr];
            const float ev = s_in[nodeB] + s_out[cB];
            eB = ev > 0.f ? ev : ALPHA * ev;
        }
    }
    float mA = eA, mB = eB;
#pragma unroll
    for (int msk = 8; msk >= 1; msk >>= 1) {
        mA = fmaxf(mA, __shfl_xor(mA, msk));
        mB = fmaxf(mB, __shfl_xor(mB, msk));
    }
    const float pA = (lr < KNB) ? __expf(eA - mA) : 0.f;
    const float pB = (lr < KNB) ? __expf(eB - mB) : 0.f;
    float sA = pA, sB = pB;
#pragma unroll
    for (int msk = 8; msk >= 1; msk >>= 1) {
        sA += __shfl_xor(sA, msk);
        sB += __shfl_xor(sB, msk);
    }
    const float attA = pA / sA * avA;
    const float attB = pB / sB * avB;

    float fA[8], fB[8];
    {
        const u32x4 sbA = selfbU4[(size_t)(vA ? nodeA : 0) * 16 + lr];
        const u32x4 sbB = selfbU4[(size_t)(vB ? nodeB : 0) * 16 + lr];
        fA[0] = bf2f(sbA[0] & 0xffffu); fA[1] = bf2f(sbA[0] >> 16);
        fA[2] = bf2f(sbA[1] & 0xffffu); fA[3] = bf2f(sbA[1] >> 16);
        fA[4] = bf2f(sbA[2] & 0xffffu); fA[5] = bf2f(sbA[2] >> 16);
        fA[6] = bf2f(sbA[3] & 0xffffu); fA[7] = bf2f(sbA[3] >> 16);
        fB[0] = bf2f(sbB[0] & 0xffffu); fB[1] = bf2f(sbB[0] >> 16);
        fB[2] = bf2f(sbB[1] & 0xffffu); fB[3] = bf2f(sbB[1] >> 16);
        fB[4] = bf2f(sbB[2] & 0xffffu); fB[5] = bf2f(sbB[2] >> 16);
        fB[6] = bf2f(sbB[3] & 0xffffu); fB[7] = bf2f(sbB[3] >> 16);
    }

    const int gb = lane & 48;
#pragma unroll
    for (int j = 0; j < KNB; ++j) {
        const float ajA = __shfl(attA, gb + j);
        const int   cjA = __shfl(cA,   gb + j);
        const float ajB = __shfl(attB, gb + j);
        const int   cjB = __shfl(cB,   gb + j);
        const u32x4 uA = hbU4[(size_t)cjA * 16 + lr];
        const u32x4 uB = hbU4[(size_t)cjB * 16 + lr];
        fA[0] = fmaf(ajA, bf2f(uA[0] & 0xffffu), fA[0]);
        fA[1] = fmaf(ajA, bf2f(uA[0] >> 16),     fA[1]);
        fA[2] = fmaf(ajA, bf2f(uA[1] & 0xffffu), fA[2]);
        fA[3] = fmaf(ajA, bf2f(uA[1] >> 16),     fA[3]);
        fA[4] = fmaf(ajA, bf2f(uA[2] & 0xffffu), fA[4]);
        fA[5] = fmaf(ajA, bf2f(uA[2] >> 16),     fA[5]);
        fA[6] = fmaf(ajA, bf2f(uA[3] & 0xffffu), fA[6]);
        fA[7] = fmaf(ajA, bf2f(uA[3] >> 16),     fA[7]);
        fB[0] = fmaf(ajB, bf2f(uB[0] & 0xffffu), fB[0]);
        fB[1] = fmaf(ajB, bf2f(uB[0] >> 16),     fB[1]);
        fB[2] = fmaf(ajB, bf2f(uB[1] & 0xffffu), fB[2]);
        fB[3] = fmaf(ajB, bf2f(uB[1] >> 16),     fB[3]);
        fB[4] = fmaf(ajB, bf2f(uB[2] & 0xffffu), fB[4]);
        fB[5] = fmaf(ajB, bf2f(uB[2] >> 16),     fB[5]);
        fB[6] = fmaf(ajB, bf2f(uB[3] & 0xffffu), fB[6]);
        fB[7] = fmaf(ajB, bf2f(uB[3] >> 16),     fB[7]);
    }

    if (vA) {
        f32x4* op = reinterpret_cast<f32x4*>(out + (size_t)nodeA * F + lr * 8);
        __builtin_nontemporal_store(f32x4{fA[0], fA[1], fA[2], fA[3]}, op);
        __builtin_nontemporal_store(f32x4{fA[4], fA[5], fA[6], fA[7]}, op + 1);
    }
    if (vB) {
        f32x4* op = reinterpret_cast<f32x4*>(out + (size_t)nodeB * F + lr * 8);
        __builtin_nontemporal_store(f32x4{fB[0], fB[1], fB[2], fB[3]}, op);
        __builtin_nontemporal_store(f32x4{fB[4], fB[5], fB[6], fB[7]}, op + 1);
    }
}

extern "C" void kernel_launch(void* const* d_in, const int* in_sizes, int n_in,
                              void* d_out, int out_size, void* d_ws, size_t ws_size,
                              hipStream_t stream) {
    const float* x     = (const float*)d_in[0];
    const float* adj   = (const float*)d_in[1];
    // d_in[2] = row: implicit (edges sorted, exactly K per node)
    const int*   col   = (const int*)d_in[3];
    const float* Wself = (const float*)d_in[4];
    const float* Wnb   = (const float*)d_in[5];
    const float* a     = (const float*)d_in[6];
    const float* bias  = (const float*)d_in[7];
    float* out = (float*)d_out;

    char* ws = (char*)d_ws;
    unsigned short* hb    = (unsigned short*)ws;         // 12,800,000 B
    unsigned short* selfb = (unsigned short*)(ws + 12800000);  // 12,800,000 B
    float* s_in  = (float*)(ws + 25600000);              // 200,000 B
    float* s_out = (float*)(ws + 25800000);              // 200,000 B
    unsigned* Wt = (unsigned*)(ws + 26000000);           // 65,536 B

    gat_prep<<<64, 256, 0, stream>>>(Wself, Wnb, Wt);
    const int ntiles = (N_NODES + BM - 1) / BM;                       // 782
    const int nblk   = (ntiles + TILES_PER_BLK - 1) / TILES_PER_BLK;  // 391
    gat_gemm<<<nblk, 512, 0, stream>>>(x, Wt, a, bias, selfb, hb, s_in, s_out);
    gat_attn<<<ATTN_NBLK, 256, 0, stream>>>((const u32x4*)hb, (const u32x4*)selfb,
                                            s_in, s_out, col, adj, out);
}